// Round 1
// baseline (7239.477 us; speedup 1.0000x reference)
//
#include <hip/hip_runtime.h>
#include <math.h>

#define HIDDEN 1024
#define HEADS 16
#define HDIM 64
#define BATCH 2
#define SEQ 2048
#define NEGV -1.0e9f
#define TOK (BATCH * SEQ * HIDDEN)            // 4,194,304
#define SC_N ((size_t)BATCH * HEADS * SEQ * SEQ)  // 134,217,728
// Fallback path only: score rows >= ROW_CUT produced by fixup kernel; (b*16+h) >= 29 <=> b=1,h>=13
#define ROW_CUT 29

// ---------------- GEMM: C[M,N] = A[M,K] @ B[K,N] + bias[N], fp32
__global__ __launch_bounds__(256) void gemm_bias(const float* __restrict__ A,
    const float* __restrict__ Bw, const float* __restrict__ bias,
    float* __restrict__ C, int M, int N, int K)
{
    __shared__ float As[64][17];
    __shared__ float Bs[16][65];
    int tid = threadIdx.x;
    int tx = tid & 15, ty = tid >> 4;
    int mBase = blockIdx.y * 64, nBase = blockIdx.x * 64;
    float acc[4][4] = {};
    int idA = tid * 4;
    int ra = idA >> 4, ca = idA & 15;   // A tile 64x16
    int rb = idA >> 6, cb = idA & 63;   // B tile 16x64
    int ty4 = ty * 4, tx4 = tx * 4;
    for (int k0 = 0; k0 < K; k0 += 16) {
        float4 fa = *(const float4*)(A + (size_t)(mBase + ra) * K + k0 + ca);
        As[ra][ca + 0] = fa.x; As[ra][ca + 1] = fa.y;
        As[ra][ca + 2] = fa.z; As[ra][ca + 3] = fa.w;
        float4 fb = *(const float4*)(Bw + (size_t)(k0 + rb) * N + nBase + cb);
        Bs[rb][cb + 0] = fb.x; Bs[rb][cb + 1] = fb.y;
        Bs[rb][cb + 2] = fb.z; Bs[rb][cb + 3] = fb.w;
        __syncthreads();
        #pragma unroll
        for (int kk = 0; kk < 16; kk++) {
            float a0 = As[ty4 + 0][kk], a1 = As[ty4 + 1][kk];
            float a2 = As[ty4 + 2][kk], a3 = As[ty4 + 3][kk];
            float b0 = Bs[kk][tx4 + 0], b1 = Bs[kk][tx4 + 1];
            float b2 = Bs[kk][tx4 + 2], b3 = Bs[kk][tx4 + 3];
            acc[0][0] += a0 * b0; acc[0][1] += a0 * b1; acc[0][2] += a0 * b2; acc[0][3] += a0 * b3;
            acc[1][0] += a1 * b0; acc[1][1] += a1 * b1; acc[1][2] += a1 * b2; acc[1][3] += a1 * b3;
            acc[2][0] += a2 * b0; acc[2][1] += a2 * b1; acc[2][2] += a2 * b2; acc[2][3] += a2 * b3;
            acc[3][0] += a3 * b0; acc[3][1] += a3 * b1; acc[3][2] += a3 * b2; acc[3][3] += a3 * b3;
        }
        __syncthreads();
    }
    #pragma unroll
    for (int i = 0; i < 4; i++) {
        int m = mBase + ty4 + i;
        #pragma unroll
        for (int j = 0; j < 4; j++) {
            int n = nBase + tx4 + j;
            C[(size_t)m * N + n] = acc[i][j] + bias[n];
        }
    }
}

// ---------------- Attention: one block per (b, h, q-row). Q in chunk0, K/V in scratch,
// ctx -> Cs. Scores written only for rows (b*16+h) < row_cut (all rows when ws path).
__global__ __launch_bounds__(256) void attn_kernel(
    const float* __restrict__ qb, const float* __restrict__ kb, const float* __restrict__ vb,
    const int* __restrict__ mask, float* __restrict__ scores_out, float* __restrict__ ctx,
    int row_cut)
{
    __shared__ float qs[HDIM];
    __shared__ float sc[SEQ];
    __shared__ float red[4];
    __shared__ float part[4][HDIM];
    int tid = threadIdx.x;
    int q = blockIdx.x, h = blockIdx.y, b = blockIdx.z;
    bool wr = (b * HEADS + h) < row_cut;

    if (tid < HDIM)
        qs[tid] = qb[((size_t)(b * SEQ + q)) * HIDDEN + h * HDIM + tid];
    __syncthreads();

    const int* mrow = mask + ((size_t)(b * SEQ + q)) * SEQ;
    const float* kbase = kb + (size_t)b * SEQ * HIDDEN + h * HDIM;
    float* srow = scores_out + (((size_t)(b * HEADS + h)) * SEQ + q) * SEQ;

    float lmax = -3.0e38f;
    for (int j = tid; j < SEQ; j += 256) {
        const float4* kp = (const float4*)(kbase + (size_t)j * HIDDEN);
        float dot = 0.f;
        #pragma unroll
        for (int c = 0; c < 16; c++) {
            float4 u = kp[c];
            dot += qs[c * 4 + 0] * u.x + qs[c * 4 + 1] * u.y
                 + qs[c * 4 + 2] * u.z + qs[c * 4 + 3] * u.w;
        }
        float s = (mrow[j] == 0) ? NEGV : dot * 0.125f;
        sc[j] = s;
        if (wr) srow[j] = s;
        lmax = fmaxf(lmax, s);
    }
    #pragma unroll
    for (int o = 32; o > 0; o >>= 1) lmax = fmaxf(lmax, __shfl_xor(lmax, o, 64));
    __syncthreads();
    if ((tid & 63) == 0) red[tid >> 6] = lmax;
    __syncthreads();
    float m = fmaxf(fmaxf(red[0], red[1]), fmaxf(red[2], red[3]));

    float lsum = 0.f;
    for (int j = tid; j < SEQ; j += 256) {
        float e = __expf(sc[j] - m);
        sc[j] = e;
        lsum += e;
    }
    #pragma unroll
    for (int o = 32; o > 0; o >>= 1) lsum += __shfl_xor(lsum, o, 64);
    __syncthreads();
    if ((tid & 63) == 0) red[tid >> 6] = lsum;
    __syncthreads();
    float inv = 1.0f / (red[0] + red[1] + red[2] + red[3]);

    int d = tid & 63, chunk = tid >> 6;
    const float* vbase = vb + (size_t)b * SEQ * HIDDEN + h * HDIM + d;
    float acc = 0.f;
    int j0 = chunk * 512;
    for (int j = j0; j < j0 + 512; j++)
        acc += sc[j] * vbase[(size_t)j * HIDDEN];
    part[chunk][d] = acc;
    __syncthreads();
    if (tid < HDIM) {
        float r = (part[0][tid] + part[1][tid] + part[2][tid] + part[3][tid]) * inv;
        ctx[((size_t)(b * SEQ + q)) * HIDDEN + h * HDIM + tid] = r;
    }
}

// ---------------- Residual + LayerNorm, in place over chunk0 (h -> out)
__global__ __launch_bounds__(256) void ln_kernel(float* __restrict__ hbuf,
    const float* __restrict__ x, const float* __restrict__ g, const float* __restrict__ bb,
    float* __restrict__ out)
{
    __shared__ float red[4];
    int row = blockIdx.x, tid = threadIdx.x;
    size_t base = (size_t)row * HIDDEN + tid * 4;
    float4 fh = *(const float4*)(hbuf + base);
    float4 fx = *(const float4*)(x + base);
    float y0 = fh.x + fx.x, y1 = fh.y + fx.y, y2 = fh.z + fx.z, y3 = fh.w + fx.w;

    float s = y0 + y1 + y2 + y3;
    #pragma unroll
    for (int o = 32; o > 0; o >>= 1) s += __shfl_xor(s, o, 64);
    if ((tid & 63) == 0) red[tid >> 6] = s;
    __syncthreads();
    float mu = (red[0] + red[1] + red[2] + red[3]) * (1.f / 1024.f);

    float d0 = y0 - mu, d1 = y1 - mu, d2 = y2 - mu, d3 = y3 - mu;
    float sq = d0 * d0 + d1 * d1 + d2 * d2 + d3 * d3;
    #pragma unroll
    for (int o = 32; o > 0; o >>= 1) sq += __shfl_xor(sq, o, 64);
    __syncthreads();
    if ((tid & 63) == 0) red[tid >> 6] = sq;
    __syncthreads();
    float var = (red[0] + red[1] + red[2] + red[3]) * (1.f / 1024.f);
    float r = rsqrtf(var + 1e-12f);

    float4 fg = *(const float4*)(g + tid * 4);
    float4 fb = *(const float4*)(bb + tid * 4);
    float4 o4;
    o4.x = d0 * r * fg.x + fb.x;
    o4.y = d1 * r * fg.y + fb.y;
    o4.z = d2 * r * fg.z + fb.z;
    o4.w = d3 * r * fg.w + fb.w;
    *(float4*)(out + base) = o4;
}

// ---------------- Score fixup (FALLBACK path only, when ws too small):
// recompute q,k from x,W for (b=1, h=13..15) tiles and write the tail score rows
// (overwrites the dead K/V/ctx scratch). Runs LAST.
__global__ __launch_bounds__(256) void score_fixup(const float* __restrict__ x,
    const float* __restrict__ Wq, const float* __restrict__ bq,
    const float* __restrict__ Wk, const float* __restrict__ bk,
    const int* __restrict__ mask, float* __restrict__ scores)
{
    __shared__ float As[64][17];
    __shared__ float Bs[16][65];
    __shared__ float qt[64][65];
    __shared__ float kt[64][65];
    const int b = 1;
    int h = 13 + blockIdx.z;
    int qBase = blockIdx.y * 64, kkBase = blockIdx.x * 64;
    int hcol = h * HDIM;
    int tid = threadIdx.x;
    int tx = tid & 15, ty = tid >> 4;
    int ty4 = ty * 4, tx4 = tx * 4;
    int idA = tid * 4;
    int ra = idA >> 4, ca = idA & 15;
    int rb = idA >> 6, cb = idA & 63;

    for (int pass = 0; pass < 2; pass++) {
        int rowBase = b * SEQ + (pass ? kkBase : qBase);
        const float* W = pass ? Wk : Wq;
        const float* bias = pass ? bk : bq;
        float acc[4][4] = {};
        for (int k0 = 0; k0 < HIDDEN; k0 += 16) {
            float4 fa = *(const float4*)(x + (size_t)(rowBase + ra) * HIDDEN + k0 + ca);
            As[ra][ca + 0] = fa.x; As[ra][ca + 1] = fa.y;
            As[ra][ca + 2] = fa.z; As[ra][ca + 3] = fa.w;
            float4 fb = *(const float4*)(W + (size_t)(k0 + rb) * HIDDEN + hcol + cb);
            Bs[rb][cb + 0] = fb.x; Bs[rb][cb + 1] = fb.y;
            Bs[rb][cb + 2] = fb.z; Bs[rb][cb + 3] = fb.w;
            __syncthreads();
            #pragma unroll
            for (int kk = 0; kk < 16; kk++) {
                float a0 = As[ty4 + 0][kk], a1 = As[ty4 + 1][kk];
                float a2 = As[ty4 + 2][kk], a3 = As[ty4 + 3][kk];
                float b0 = Bs[kk][tx4 + 0], b1 = Bs[kk][tx4 + 1];
                float b2 = Bs[kk][tx4 + 2], b3 = Bs[kk][tx4 + 3];
                acc[0][0] += a0 * b0; acc[0][1] += a0 * b1; acc[0][2] += a0 * b2; acc[0][3] += a0 * b3;
                acc[1][0] += a1 * b0; acc[1][1] += a1 * b1; acc[1][2] += a1 * b2; acc[1][3] += a1 * b3;
                acc[2][0] += a2 * b0; acc[2][1] += a2 * b1; acc[2][2] += a2 * b2; acc[2][3] += a2 * b3;
                acc[3][0] += a3 * b0; acc[3][1] += a3 * b1; acc[3][2] += a3 * b2; acc[3][3] += a3 * b3;
            }
            __syncthreads();
        }
        #pragma unroll
        for (int i = 0; i < 4; i++)
            #pragma unroll
            for (int j = 0; j < 4; j++) {
                float v = acc[i][j] + bias[hcol + tx4 + j];
                if (pass) kt[ty4 + i][tx4 + j] = v;
                else      qt[ty4 + i][tx4 + j] = v;
            }
        __syncthreads();
    }

    float s[4][4] = {};
    for (int d = 0; d < HDIM; d++) {
        float qv0 = qt[ty4 + 0][d], qv1 = qt[ty4 + 1][d];
        float qv2 = qt[ty4 + 2][d], qv3 = qt[ty4 + 3][d];
        float kv0 = kt[tx4 + 0][d], kv1 = kt[tx4 + 1][d];
        float kv2 = kt[tx4 + 2][d], kv3 = kt[tx4 + 3][d];
        s[0][0] += qv0 * kv0; s[0][1] += qv0 * kv1; s[0][2] += qv0 * kv2; s[0][3] += qv0 * kv3;
        s[1][0] += qv1 * kv0; s[1][1] += qv1 * kv1; s[1][2] += qv1 * kv2; s[1][3] += qv1 * kv3;
        s[2][0] += qv2 * kv0; s[2][1] += qv2 * kv1; s[2][2] += qv2 * kv2; s[2][3] += qv2 * kv3;
        s[3][0] += qv3 * kv0; s[3][1] += qv3 * kv1; s[3][2] += qv3 * kv2; s[3][3] += qv3 * kv3;
    }
    #pragma unroll
    for (int i = 0; i < 4; i++) {
        int q = qBase + ty4 + i;
        const int* mrow = mask + ((size_t)(b * SEQ + q)) * SEQ;
        float* srow = scores + (((size_t)(b * HEADS + h)) * SEQ + q) * SEQ;
        #pragma unroll
        for (int j = 0; j < 4; j++) {
            int kk = kkBase + tx4 + j;
            srow[kk] = (mrow[kk] == 0) ? NEGV : s[i][j] * 0.125f;
        }
    }
}

extern "C" void kernel_launch(void* const* d_in, const int* in_sizes, int n_in,
                              void* d_out, int out_size, void* d_ws, size_t ws_size,
                              hipStream_t stream)
{
    const float* x   = (const float*)d_in[0];
    const int*   msk = (const int*)d_in[1];
    const float* Wq  = (const float*)d_in[2];
    const float* bq  = (const float*)d_in[3];
    const float* Wk  = (const float*)d_in[4];
    const float* bk  = (const float*)d_in[5];
    const float* Wv  = (const float*)d_in[6];
    const float* bv  = (const float*)d_in[7];
    const float* Wo  = (const float*)d_in[8];
    const float* bo  = (const float*)d_in[9];
    const float* lng = (const float*)d_in[10];
    const float* lnb = (const float*)d_in[11];

    float* out0   = (float*)d_out;                 // chunk 0: [B*S, HIDDEN]
    float* scores = out0 + (size_t)TOK;            // chunk 1: [B,H,S,S]

    // Preferred: K/V/ctx scratch in the provided workspace -> attn writes ALL score
    // rows directly and the (expensive, ~103 GFLOP) score_fixup recompute is skipped.
    const size_t need = (size_t)3 * TOK * sizeof(float);   // 48 MiB
    const bool use_ws = (d_ws != nullptr) && (ws_size >= need);

    float* Ks;
    float* Vs;
    float* Cs;
    int row_cut;
    if (use_ws) {
        Ks = (float*)d_ws;
        Vs = Ks + (size_t)TOK;
        Cs = Vs + (size_t)TOK;
        row_cut = BATCH * HEADS;   // 32: every (b,h) row written by attn_kernel
    } else {
        // Fallback: scratch carved from the TAIL of the score region
        // (rows b=1,h>=13, regenerated by score_fixup last)
        Ks = scores + (SC_N - (size_t)3 * TOK);
        Vs = Ks + (size_t)TOK;
        Cs = Vs + (size_t)TOK;
        row_cut = ROW_CUT;
    }
    float* Qs = out0;   // Q staged in chunk0; overwritten by h after attention

    const int M = BATCH * SEQ;
    dim3 gg(HIDDEN / 64, M / 64);
    gemm_bias<<<gg, 256, 0, stream>>>(x, Wq, bq, Qs, M, HIDDEN, HIDDEN);
    gemm_bias<<<gg, 256, 0, stream>>>(x, Wk, bk, Ks, M, HIDDEN, HIDDEN);
    gemm_bias<<<gg, 256, 0, stream>>>(x, Wv, bv, Vs, M, HIDDEN, HIDDEN);
    attn_kernel<<<dim3(SEQ, HEADS, BATCH), 256, 0, stream>>>(Qs, Ks, Vs, msk, scores, Cs, row_cut);
    gemm_bias<<<gg, 256, 0, stream>>>(Cs, Wo, bo, out0, M, HIDDEN, HIDDEN);  // h -> chunk0
    ln_kernel<<<M, 256, 0, stream>>>(out0, x, lng, lnb, out0);
    if (!use_ws)
        score_fixup<<<dim3(SEQ / 64, SEQ / 64, 3), 256, 0, stream>>>(x, Wq, bq, Wk, bk, msk, scores);
}

// Round 2
// 1921.974 us; speedup vs baseline: 3.7667x; 3.7667x over previous
//
#include <hip/hip_runtime.h>
#include <math.h>

#define HIDDEN 1024
#define HEADS 16
#define HDIM 64
#define BATCH 2
#define SEQ 2048
#define NEGV -1.0e9f
#define TOK (BATCH * SEQ * HIDDEN)            // 4,194,304
#define SC_N ((size_t)BATCH * HEADS * SEQ * SEQ)  // 134,217,728
// Fallback path only: score rows >= ROW_CUT produced by fixup kernel; (b*16+h) >= 29 <=> b=1,h>=13
#define ROW_CUT 29

// ---------------- GEMM: C[M,N] = A[M,K] @ B[K,N] + bias[N], fp32
__global__ __launch_bounds__(256) void gemm_bias(const float* __restrict__ A,
    const float* __restrict__ Bw, const float* __restrict__ bias,
    float* __restrict__ C, int M, int N, int K)
{
    __shared__ float As[64][17];
    __shared__ float Bs[16][65];
    int tid = threadIdx.x;
    int tx = tid & 15, ty = tid >> 4;
    int mBase = blockIdx.y * 64, nBase = blockIdx.x * 64;
    float acc[4][4] = {};
    int idA = tid * 4;
    int ra = idA >> 4, ca = idA & 15;   // A tile 64x16
    int rb = idA >> 6, cb = idA & 63;   // B tile 16x64
    int ty4 = ty * 4, tx4 = tx * 4;
    for (int k0 = 0; k0 < K; k0 += 16) {
        float4 fa = *(const float4*)(A + (size_t)(mBase + ra) * K + k0 + ca);
        As[ra][ca + 0] = fa.x; As[ra][ca + 1] = fa.y;
        As[ra][ca + 2] = fa.z; As[ra][ca + 3] = fa.w;
        float4 fb = *(const float4*)(Bw + (size_t)(k0 + rb) * N + nBase + cb);
        Bs[rb][cb + 0] = fb.x; Bs[rb][cb + 1] = fb.y;
        Bs[rb][cb + 2] = fb.z; Bs[rb][cb + 3] = fb.w;
        __syncthreads();
        #pragma unroll
        for (int kk = 0; kk < 16; kk++) {
            float a0 = As[ty4 + 0][kk], a1 = As[ty4 + 1][kk];
            float a2 = As[ty4 + 2][kk], a3 = As[ty4 + 3][kk];
            float b0 = Bs[kk][tx4 + 0], b1 = Bs[kk][tx4 + 1];
            float b2 = Bs[kk][tx4 + 2], b3 = Bs[kk][tx4 + 3];
            acc[0][0] += a0 * b0; acc[0][1] += a0 * b1; acc[0][2] += a0 * b2; acc[0][3] += a0 * b3;
            acc[1][0] += a1 * b0; acc[1][1] += a1 * b1; acc[1][2] += a1 * b2; acc[1][3] += a1 * b3;
            acc[2][0] += a2 * b0; acc[2][1] += a2 * b1; acc[2][2] += a2 * b2; acc[2][3] += a2 * b3;
            acc[3][0] += a3 * b0; acc[3][1] += a3 * b1; acc[3][2] += a3 * b2; acc[3][3] += a3 * b3;
        }
        __syncthreads();
    }
    #pragma unroll
    for (int i = 0; i < 4; i++) {
        int m = mBase + ty4 + i;
        #pragma unroll
        for (int j = 0; j < 4; j++) {
            int n = nBase + tx4 + j;
            C[(size_t)m * N + n] = acc[i][j] + bias[n];
        }
    }
}

// ---------------- Tiled attention with online softmax (ws path).
// One block per (b, h, 64-row q-tile). Per 64-wide k-tile: stage K/V in LDS,
// S-tile = Q K^T via 4x4 register blocking, mask+scale+write raw scores,
// online-max rescale (16-lane shfl butterflies, all in registers),
// E = exp(S - m) staged in LDS, ctx-acc += E @ V. All LDS patterns are the
// proven conflict-free (row+col)%32 2-way pattern from gemm_bias.
__global__ __launch_bounds__(256) void attn_tile(
    const float* __restrict__ qb, const float* __restrict__ kb, const float* __restrict__ vb,
    const int* __restrict__ mask, float* __restrict__ scores_out, float* __restrict__ ctx)
{
    __shared__ float Qs[64][65];
    __shared__ float Ksh[64][65];
    __shared__ float Vsh[64][65];
    __shared__ float Es[64][65];

    int tid = threadIdx.x;
    int tx = tid & 15, ty = tid >> 4;
    int tx4 = tx * 4, ty4 = ty * 4;
    int qBase = blockIdx.x * 64;
    int h = blockIdx.y, b = blockIdx.z;

    const float* qsrc  = qb + ((size_t)(b * SEQ + qBase)) * HIDDEN + h * HDIM;
    const float* kbase = kb + (size_t)b * SEQ * HIDDEN + h * HDIM;
    const float* vbase = vb + (size_t)b * SEQ * HIDDEN + h * HDIM;
    const int*   mbase = mask + ((size_t)(b * SEQ + qBase)) * SEQ;
    float*       sbase = scores_out + (((size_t)(b * HEADS + h)) * SEQ + qBase) * SEQ;

    // stage Q tile [64 q][64 d] (coalesced float4; covered by first loop's sync)
    #pragma unroll
    for (int rr = 0; rr < 4; rr++) {
        int r = rr * 16 + ty;
        float4 f = *(const float4*)(qsrc + (size_t)r * HIDDEN + tx4);
        Qs[r][tx4 + 0] = f.x; Qs[r][tx4 + 1] = f.y;
        Qs[r][tx4 + 2] = f.z; Qs[r][tx4 + 3] = f.w;
    }

    float c[4][4] = {};
    float mrow[4] = {-3.0e38f, -3.0e38f, -3.0e38f, -3.0e38f};
    float rsum[4] = {0.f, 0.f, 0.f, 0.f};

    for (int kt = 0; kt < SEQ; kt += 64) {
        // stage K,V tiles [64 k][64 d]
        #pragma unroll
        for (int rr = 0; rr < 4; rr++) {
            int r = rr * 16 + ty;
            float4 fk = *(const float4*)(kbase + (size_t)(kt + r) * HIDDEN + tx4);
            Ksh[r][tx4 + 0] = fk.x; Ksh[r][tx4 + 1] = fk.y;
            Ksh[r][tx4 + 2] = fk.z; Ksh[r][tx4 + 3] = fk.w;
            float4 fv = *(const float4*)(vbase + (size_t)(kt + r) * HIDDEN + tx4);
            Vsh[r][tx4 + 0] = fv.x; Vsh[r][tx4 + 1] = fv.y;
            Vsh[r][tx4 + 2] = fv.z; Vsh[r][tx4 + 3] = fv.w;
        }
        __syncthreads();

        // S tile: s[i][j] = Q[ty4+i] . K[tx4+j]
        float s[4][4] = {};
        #pragma unroll 8
        for (int d = 0; d < 64; d++) {
            float a0 = Qs[ty4 + 0][d], a1 = Qs[ty4 + 1][d];
            float a2 = Qs[ty4 + 2][d], a3 = Qs[ty4 + 3][d];
            float b0 = Ksh[tx4 + 0][d], b1 = Ksh[tx4 + 1][d];
            float b2 = Ksh[tx4 + 2][d], b3 = Ksh[tx4 + 3][d];
            s[0][0] += a0 * b0; s[0][1] += a0 * b1; s[0][2] += a0 * b2; s[0][3] += a0 * b3;
            s[1][0] += a1 * b0; s[1][1] += a1 * b1; s[1][2] += a1 * b2; s[1][3] += a1 * b3;
            s[2][0] += a2 * b0; s[2][1] += a2 * b1; s[2][2] += a2 * b2; s[2][3] += a2 * b3;
            s[3][0] += a3 * b0; s[3][1] += a3 * b1; s[3][2] += a3 * b2; s[3][3] += a3 * b3;
        }

        // mask + scale, write raw scores (coalesced float4)
        #pragma unroll
        for (int i = 0; i < 4; i++) {
            int qi = ty4 + i;
            int4 mm = *(const int4*)(mbase + (size_t)qi * SEQ + kt + tx4);
            float4 sv;
            sv.x = (mm.x == 0) ? NEGV : s[i][0] * 0.125f;
            sv.y = (mm.y == 0) ? NEGV : s[i][1] * 0.125f;
            sv.z = (mm.z == 0) ? NEGV : s[i][2] * 0.125f;
            sv.w = (mm.w == 0) ? NEGV : s[i][3] * 0.125f;
            *(float4*)(sbase + (size_t)qi * SEQ + kt + tx4) = sv;
            s[i][0] = sv.x; s[i][1] = sv.y; s[i][2] = sv.z; s[i][3] = sv.w;
        }

        // online softmax update per row (all 16 tx lanes compute identical m/rsum)
        #pragma unroll
        for (int i = 0; i < 4; i++) {
            float tmax = fmaxf(fmaxf(s[i][0], s[i][1]), fmaxf(s[i][2], s[i][3]));
            #pragma unroll
            for (int o = 1; o < 16; o <<= 1)
                tmax = fmaxf(tmax, __shfl_xor(tmax, o, 64));
            float mn  = fmaxf(mrow[i], tmax);
            float fac = __expf(mrow[i] - mn);
            mrow[i] = mn;
            float e0 = __expf(s[i][0] - mn), e1 = __expf(s[i][1] - mn);
            float e2 = __expf(s[i][2] - mn), e3 = __expf(s[i][3] - mn);
            Es[ty4 + i][tx4 + 0] = e0; Es[ty4 + i][tx4 + 1] = e1;
            Es[ty4 + i][tx4 + 2] = e2; Es[ty4 + i][tx4 + 3] = e3;
            float ts = e0 + e1 + e2 + e3;
            #pragma unroll
            for (int o = 1; o < 16; o <<= 1)
                ts += __shfl_xor(ts, o, 64);
            rsum[i] = rsum[i] * fac + ts;
            c[i][0] *= fac; c[i][1] *= fac; c[i][2] *= fac; c[i][3] *= fac;
        }
        __syncthreads();   // Es complete

        // ctx-acc += E @ V
        #pragma unroll 8
        for (int kk = 0; kk < 64; kk++) {
            float a0 = Es[ty4 + 0][kk], a1 = Es[ty4 + 1][kk];
            float a2 = Es[ty4 + 2][kk], a3 = Es[ty4 + 3][kk];
            float b0 = Vsh[kk][tx4 + 0], b1 = Vsh[kk][tx4 + 1];
            float b2 = Vsh[kk][tx4 + 2], b3 = Vsh[kk][tx4 + 3];
            c[0][0] += a0 * b0; c[0][1] += a0 * b1; c[0][2] += a0 * b2; c[0][3] += a0 * b3;
            c[1][0] += a1 * b0; c[1][1] += a1 * b1; c[1][2] += a1 * b2; c[1][3] += a1 * b3;
            c[2][0] += a2 * b0; c[2][1] += a2 * b1; c[2][2] += a2 * b2; c[2][3] += a2 * b3;
            c[3][0] += a3 * b0; c[3][1] += a3 * b1; c[3][2] += a3 * b2; c[3][3] += a3 * b3;
        }
        __syncthreads();   // before restaging K/V/Es
    }

    #pragma unroll
    for (int i = 0; i < 4; i++) {
        float inv = 1.0f / rsum[i];
        float4 o4;
        o4.x = c[i][0] * inv; o4.y = c[i][1] * inv;
        o4.z = c[i][2] * inv; o4.w = c[i][3] * inv;
        *(float4*)(ctx + ((size_t)(b * SEQ + qBase + ty4 + i)) * HIDDEN + h * HDIM + tx4) = o4;
    }
}

// ---------------- Attention fallback (one block per q-row), used only if ws too small
__global__ __launch_bounds__(256) void attn_kernel(
    const float* __restrict__ qb, const float* __restrict__ kb, const float* __restrict__ vb,
    const int* __restrict__ mask, float* __restrict__ scores_out, float* __restrict__ ctx,
    int row_cut)
{
    __shared__ float qs[HDIM];
    __shared__ float sc[SEQ];
    __shared__ float red[4];
    __shared__ float part[4][HDIM];
    int tid = threadIdx.x;
    int q = blockIdx.x, h = blockIdx.y, b = blockIdx.z;
    bool wr = (b * HEADS + h) < row_cut;

    if (tid < HDIM)
        qs[tid] = qb[((size_t)(b * SEQ + q)) * HIDDEN + h * HDIM + tid];
    __syncthreads();

    const int* mrow = mask + ((size_t)(b * SEQ + q)) * SEQ;
    const float* kbase = kb + (size_t)b * SEQ * HIDDEN + h * HDIM;
    float* srow = scores_out + (((size_t)(b * HEADS + h)) * SEQ + q) * SEQ;

    float lmax = -3.0e38f;
    for (int j = tid; j < SEQ; j += 256) {
        const float4* kp = (const float4*)(kbase + (size_t)j * HIDDEN);
        float dot = 0.f;
        #pragma unroll
        for (int c = 0; c < 16; c++) {
            float4 u = kp[c];
            dot += qs[c * 4 + 0] * u.x + qs[c * 4 + 1] * u.y
                 + qs[c * 4 + 2] * u.z + qs[c * 4 + 3] * u.w;
        }
        float s = (mrow[j] == 0) ? NEGV : dot * 0.125f;
        sc[j] = s;
        if (wr) srow[j] = s;
        lmax = fmaxf(lmax, s);
    }
    #pragma unroll
    for (int o = 32; o > 0; o >>= 1) lmax = fmaxf(lmax, __shfl_xor(lmax, o, 64));
    __syncthreads();
    if ((tid & 63) == 0) red[tid >> 6] = lmax;
    __syncthreads();
    float m = fmaxf(fmaxf(red[0], red[1]), fmaxf(red[2], red[3]));

    float lsum = 0.f;
    for (int j = tid; j < SEQ; j += 256) {
        float e = __expf(sc[j] - m);
        sc[j] = e;
        lsum += e;
    }
    #pragma unroll
    for (int o = 32; o > 0; o >>= 1) lsum += __shfl_xor(lsum, o, 64);
    __syncthreads();
    if ((tid & 63) == 0) red[tid >> 6] = lsum;
    __syncthreads();
    float inv = 1.0f / (red[0] + red[1] + red[2] + red[3]);

    int d = tid & 63, chunk = tid >> 6;
    const float* vbase = vb + (size_t)b * SEQ * HIDDEN + h * HDIM + d;
    float acc = 0.f;
    int j0 = chunk * 512;
    for (int j = j0; j < j0 + 512; j++)
        acc += sc[j] * vbase[(size_t)j * HIDDEN];
    part[chunk][d] = acc;
    __syncthreads();
    if (tid < HDIM) {
        float r = (part[0][tid] + part[1][tid] + part[2][tid] + part[3][tid]) * inv;
        ctx[((size_t)(b * SEQ + q)) * HIDDEN + h * HDIM + tid] = r;
    }
}

// ---------------- Residual + LayerNorm, in place over chunk0 (h -> out)
__global__ __launch_bounds__(256) void ln_kernel(float* __restrict__ hbuf,
    const float* __restrict__ x, const float* __restrict__ g, const float* __restrict__ bb,
    float* __restrict__ out)
{
    __shared__ float red[4];
    int row = blockIdx.x, tid = threadIdx.x;
    size_t base = (size_t)row * HIDDEN + tid * 4;
    float4 fh = *(const float4*)(hbuf + base);
    float4 fx = *(const float4*)(x + base);
    float y0 = fh.x + fx.x, y1 = fh.y + fx.y, y2 = fh.z + fx.z, y3 = fh.w + fx.w;

    float s = y0 + y1 + y2 + y3;
    #pragma unroll
    for (int o = 32; o > 0; o >>= 1) s += __shfl_xor(s, o, 64);
    if ((tid & 63) == 0) red[tid >> 6] = s;
    __syncthreads();
    float mu = (red[0] + red[1] + red[2] + red[3]) * (1.f / 1024.f);

    float d0 = y0 - mu, d1 = y1 - mu, d2 = y2 - mu, d3 = y3 - mu;
    float sq = d0 * d0 + d1 * d1 + d2 * d2 + d3 * d3;
    #pragma unroll
    for (int o = 32; o > 0; o >>= 1) sq += __shfl_xor(sq, o, 64);
    __syncthreads();
    if ((tid & 63) == 0) red[tid >> 6] = sq;
    __syncthreads();
    float var = (red[0] + red[1] + red[2] + red[3]) * (1.f / 1024.f);
    float r = rsqrtf(var + 1e-12f);

    float4 fg = *(const float4*)(g + tid * 4);
    float4 fb = *(const float4*)(bb + tid * 4);
    float4 o4;
    o4.x = d0 * r * fg.x + fb.x;
    o4.y = d1 * r * fg.y + fb.y;
    o4.z = d2 * r * fg.z + fb.z;
    o4.w = d3 * r * fg.w + fb.w;
    *(float4*)(out + base) = o4;
}

// ---------------- Score fixup (FALLBACK path only, when ws too small)
__global__ __launch_bounds__(256) void score_fixup(const float* __restrict__ x,
    const float* __restrict__ Wq, const float* __restrict__ bq,
    const float* __restrict__ Wk, const float* __restrict__ bk,
    const int* __restrict__ mask, float* __restrict__ scores)
{
    __shared__ float As[64][17];
    __shared__ float Bs[16][65];
    __shared__ float qt[64][65];
    __shared__ float kt[64][65];
    const int b = 1;
    int h = 13 + blockIdx.z;
    int qBase = blockIdx.y * 64, kkBase = blockIdx.x * 64;
    int hcol = h * HDIM;
    int tid = threadIdx.x;
    int tx = tid & 15, ty = tid >> 4;
    int ty4 = ty * 4, tx4 = tx * 4;
    int idA = tid * 4;
    int ra = idA >> 4, ca = idA & 15;
    int rb = idA >> 6, cb = idA & 63;

    for (int pass = 0; pass < 2; pass++) {
        int rowBase = b * SEQ + (pass ? kkBase : qBase);
        const float* W = pass ? Wk : Wq;
        const float* bias = pass ? bk : bq;
        float acc[4][4] = {};
        for (int k0 = 0; k0 < HIDDEN; k0 += 16) {
            float4 fa = *(const float4*)(x + (size_t)(rowBase + ra) * HIDDEN + k0 + ca);
            As[ra][ca + 0] = fa.x; As[ra][ca + 1] = fa.y;
            As[ra][ca + 2] = fa.z; As[ra][ca + 3] = fa.w;
            float4 fb = *(const float4*)(W + (size_t)(k0 + rb) * HIDDEN + hcol + cb);
            Bs[rb][cb + 0] = fb.x; Bs[rb][cb + 1] = fb.y;
            Bs[rb][cb + 2] = fb.z; Bs[rb][cb + 3] = fb.w;
            __syncthreads();
            #pragma unroll
            for (int kk = 0; kk < 16; kk++) {
                float a0 = As[ty4 + 0][kk], a1 = As[ty4 + 1][kk];
                float a2 = As[ty4 + 2][kk], a3 = As[ty4 + 3][kk];
                float b0 = Bs[kk][tx4 + 0], b1 = Bs[kk][tx4 + 1];
                float b2 = Bs[kk][tx4 + 2], b3 = Bs[kk][tx4 + 3];
                acc[0][0] += a0 * b0; acc[0][1] += a0 * b1; acc[0][2] += a0 * b2; acc[0][3] += a0 * b3;
                acc[1][0] += a1 * b0; acc[1][1] += a1 * b1; acc[1][2] += a1 * b2; acc[1][3] += a1 * b3;
                acc[2][0] += a2 * b0; acc[2][1] += a2 * b1; acc[2][2] += a2 * b2; acc[2][3] += a2 * b3;
                acc[3][0] += a3 * b0; acc[3][1] += a3 * b1; acc[3][2] += a3 * b2; acc[3][3] += a3 * b3;
            }
            __syncthreads();
        }
        #pragma unroll
        for (int i = 0; i < 4; i++)
            #pragma unroll
            for (int j = 0; j < 4; j++) {
                float v = acc[i][j] + bias[hcol + tx4 + j];
                if (pass) kt[ty4 + i][tx4 + j] = v;
                else      qt[ty4 + i][tx4 + j] = v;
            }
        __syncthreads();
    }

    float s[4][4] = {};
    for (int d = 0; d < HDIM; d++) {
        float qv0 = qt[ty4 + 0][d], qv1 = qt[ty4 + 1][d];
        float qv2 = qt[ty4 + 2][d], qv3 = qt[ty4 + 3][d];
        float kv0 = kt[tx4 + 0][d], kv1 = kt[tx4 + 1][d];
        float kv2 = kt[tx4 + 2][d], kv3 = kt[tx4 + 3][d];
        s[0][0] += qv0 * kv0; s[0][1] += qv0 * kv1; s[0][2] += qv0 * kv2; s[0][3] += qv0 * kv3;
        s[1][0] += qv1 * kv0; s[1][1] += qv1 * kv1; s[1][2] += qv1 * kv2; s[1][3] += qv1 * kv3;
        s[2][0] += qv2 * kv0; s[2][1] += qv2 * kv1; s[2][2] += qv2 * kv2; s[2][3] += qv2 * kv3;
        s[3][0] += qv3 * kv0; s[3][1] += qv3 * kv1; s[3][2] += qv3 * kv2; s[3][3] += qv3 * kv3;
    }
    #pragma unroll
    for (int i = 0; i < 4; i++) {
        int q = qBase + ty4 + i;
        const int* mrow = mask + ((size_t)(b * SEQ + q)) * SEQ;
        float* srow = scores + (((size_t)(b * HEADS + h)) * SEQ + q) * SEQ;
        #pragma unroll
        for (int j = 0; j < 4; j++) {
            int kk = kkBase + tx4 + j;
            srow[kk] = (mrow[kk] == 0) ? NEGV : s[i][j] * 0.125f;
        }
    }
}

extern "C" void kernel_launch(void* const* d_in, const int* in_sizes, int n_in,
                              void* d_out, int out_size, void* d_ws, size_t ws_size,
                              hipStream_t stream)
{
    const float* x   = (const float*)d_in[0];
    const int*   msk = (const int*)d_in[1];
    const float* Wq  = (const float*)d_in[2];
    const float* bq  = (const float*)d_in[3];
    const float* Wk  = (const float*)d_in[4];
    const float* bk  = (const float*)d_in[5];
    const float* Wv  = (const float*)d_in[6];
    const float* bv  = (const float*)d_in[7];
    const float* Wo  = (const float*)d_in[8];
    const float* bo  = (const float*)d_in[9];
    const float* lng = (const float*)d_in[10];
    const float* lnb = (const float*)d_in[11];

    float* out0   = (float*)d_out;                 // chunk 0: [B*S, HIDDEN]
    float* scores = out0 + (size_t)TOK;            // chunk 1: [B,H,S,S]

    const size_t need = (size_t)3 * TOK * sizeof(float);   // 48 MiB
    const bool use_ws = (d_ws != nullptr) && (ws_size >= need);

    float* Ks;
    float* Vs;
    float* Cs;
    if (use_ws) {
        Ks = (float*)d_ws;
        Vs = Ks + (size_t)TOK;
        Cs = Vs + (size_t)TOK;
    } else {
        Ks = scores + (SC_N - (size_t)3 * TOK);
        Vs = Ks + (size_t)TOK;
        Cs = Vs + (size_t)TOK;
    }
    float* Qs = out0;   // Q staged in chunk0; overwritten by h after attention

    const int M = BATCH * SEQ;
    dim3 gg(HIDDEN / 64, M / 64);
    gemm_bias<<<gg, 256, 0, stream>>>(x, Wq, bq, Qs, M, HIDDEN, HIDDEN);
    gemm_bias<<<gg, 256, 0, stream>>>(x, Wk, bk, Ks, M, HIDDEN, HIDDEN);
    gemm_bias<<<gg, 256, 0, stream>>>(x, Wv, bv, Vs, M, HIDDEN, HIDDEN);
    if (use_ws) {
        attn_tile<<<dim3(SEQ / 64, HEADS, BATCH), 256, 0, stream>>>(Qs, Ks, Vs, msk, scores, Cs);
    } else {
        attn_kernel<<<dim3(SEQ, HEADS, BATCH), 256, 0, stream>>>(Qs, Ks, Vs, msk, scores, Cs, ROW_CUT);
    }
    gemm_bias<<<gg, 256, 0, stream>>>(Cs, Wo, bo, out0, M, HIDDEN, HIDDEN);  // h -> chunk0
    ln_kernel<<<M, 256, 0, stream>>>(out0, x, lng, lnb, out0);
    if (!use_ws)
        score_fixup<<<dim3(SEQ / 64, SEQ / 64, 3), 256, 0, stream>>>(x, Wq, bq, Wk, bk, msk, scores);
}

// Round 3
// 1091.416 us; speedup vs baseline: 6.6331x; 1.7610x over previous
//
#include <hip/hip_runtime.h>
#include <math.h>

#define HIDDEN 1024
#define HEADS 16
#define HDIM 64
#define BATCH 2
#define SEQ 2048
#define NEGV -1.0e9f
#define TOK (BATCH * SEQ * HIDDEN)            // 4,194,304
#define SC_N ((size_t)BATCH * HEADS * SEQ * SEQ)  // 134,217,728
#define ROW_CUT 29
#define PIT 72   // LDS pitch in bf16 elems: 144B rows -> 16B aligned, 2-way banks on b128

typedef __bf16 bf16x8 __attribute__((ext_vector_type(8)));
typedef float f32x4 __attribute__((ext_vector_type(4)));

__device__ __forceinline__ unsigned short f2bf(float f) {
    union { float f; unsigned u; } v; v.f = f;
    unsigned r = (v.u + 0x7fffu + ((v.u >> 16) & 1u)) >> 16;
    return (unsigned short)r;
}
__device__ __forceinline__ float bf2f(unsigned short h) {
    union { unsigned u; float f; } v; v.u = ((unsigned)h) << 16;
    return v.f;
}
__device__ __forceinline__ void split_bf(float v, unsigned short& h, unsigned short& l) {
    h = f2bf(v);
    l = f2bf(v - bf2f(h));
}
__device__ __forceinline__ bf16x8 ld_frag(const unsigned short* p) {
    union { uint4 u; bf16x8 v; } t;
    t.u = *(const uint4*)p;
    return t.v;
}

// ---------------- MFMA GEMM: C[M,N] = A[M,K] @ B[K,N] + bias, bf16 hi/lo 3-product split.
// PRESPLIT: A given as (Ahi,Alo) bf16 arrays. SPLITOUT: emit (Ohi,Olo) bf16 instead of fp32 C.
// BM=128, BN=64, BK=64. 256 threads = 4 waves (2M x 2N), wave tile 64x32.
template<int PRESPLIT, int SPLITOUT>
__global__ __launch_bounds__(256) void mfma_gemm(
    const float* __restrict__ A,
    const unsigned short* __restrict__ Ahi, const unsigned short* __restrict__ Alo,
    const float* __restrict__ Bw, const float* __restrict__ bias,
    float* __restrict__ C,
    unsigned short* __restrict__ Ohi, unsigned short* __restrict__ Olo,
    int M, int N, int K)
{
    __shared__ unsigned short Ah[128][PIT], Al[128][PIT];
    __shared__ unsigned short Bh[64][PIT], Bl[64][PIT];
    int tid = threadIdx.x;
    int lane = tid & 63, wv = tid >> 6;
    int wm = wv >> 1, wn = wv & 1;
    int l15 = lane & 15, l4 = lane >> 4;
    int mBase = blockIdx.y * 128, nBase = blockIdx.x * 64;

    f32x4 acc[4][2] = {};

    for (int kt = 0; kt < K; kt += 64) {
        // ---- stage A tile [128][64]
        if (PRESPLIT) {
            int r = tid >> 3, g = tid & 7;
            #pragma unroll
            for (int i = 0; i < 4; i++) {
                int rr = r + i * 32;
                size_t gofs = (size_t)(mBase + rr) * K + kt + g * 8;
                *(uint4*)&Ah[rr][g * 8] = *(const uint4*)&Ahi[gofs];
                *(uint4*)&Al[rr][g * 8] = *(const uint4*)&Alo[gofs];
            }
        } else {
            int r = tid >> 4, c4 = (tid & 15) * 4;
            #pragma unroll
            for (int i = 0; i < 8; i++) {
                int rr = r + i * 16;
                float4 f = *(const float4*)&A[(size_t)(mBase + rr) * K + kt + c4];
                unsigned short h0, h1, h2, h3, q0, q1, q2, q3;
                split_bf(f.x, h0, q0); split_bf(f.y, h1, q1);
                split_bf(f.z, h2, q2); split_bf(f.w, h3, q3);
                uint2 ph, pl;
                ph.x = (unsigned)h0 | ((unsigned)h1 << 16);
                ph.y = (unsigned)h2 | ((unsigned)h3 << 16);
                pl.x = (unsigned)q0 | ((unsigned)q1 << 16);
                pl.y = (unsigned)q2 | ((unsigned)q3 << 16);
                *(uint2*)&Ah[rr][c4] = ph;
                *(uint2*)&Al[rr][c4] = pl;
            }
        }
        // ---- stage B tile [64][64] transposed -> [ncol][k]
        {
            int r = tid >> 4, c4 = (tid & 15) * 4;
            #pragma unroll
            for (int i = 0; i < 4; i++) {
                int rr = r + i * 16;
                float4 f = *(const float4*)&Bw[(size_t)(kt + rr) * N + nBase + c4];
                unsigned short h, l;
                split_bf(f.x, h, l); Bh[c4 + 0][rr] = h; Bl[c4 + 0][rr] = l;
                split_bf(f.y, h, l); Bh[c4 + 1][rr] = h; Bl[c4 + 1][rr] = l;
                split_bf(f.z, h, l); Bh[c4 + 2][rr] = h; Bl[c4 + 2][rr] = l;
                split_bf(f.w, h, l); Bh[c4 + 3][rr] = h; Bl[c4 + 3][rr] = l;
            }
        }
        __syncthreads();

        #pragma unroll
        for (int ks = 0; ks < 64; ks += 32) {
            int ko = ks + l4 * 8;
            bf16x8 aH[4], aL[4], bH[2], bL[2];
            #pragma unroll
            for (int ti = 0; ti < 4; ti++) {
                aH[ti] = ld_frag(&Ah[wm * 64 + ti * 16 + l15][ko]);
                aL[ti] = ld_frag(&Al[wm * 64 + ti * 16 + l15][ko]);
            }
            #pragma unroll
            for (int tj = 0; tj < 2; tj++) {
                bH[tj] = ld_frag(&Bh[wn * 32 + tj * 16 + l15][ko]);
                bL[tj] = ld_frag(&Bl[wn * 32 + tj * 16 + l15][ko]);
            }
            #pragma unroll
            for (int ti = 0; ti < 4; ti++)
                #pragma unroll
                for (int tj = 0; tj < 2; tj++) {
                    acc[ti][tj] = __builtin_amdgcn_mfma_f32_16x16x32_bf16(aH[ti], bH[tj], acc[ti][tj], 0, 0, 0);
                    acc[ti][tj] = __builtin_amdgcn_mfma_f32_16x16x32_bf16(aH[ti], bL[tj], acc[ti][tj], 0, 0, 0);
                    acc[ti][tj] = __builtin_amdgcn_mfma_f32_16x16x32_bf16(aL[ti], bH[tj], acc[ti][tj], 0, 0, 0);
                }
        }
        __syncthreads();
    }

    // ---- epilogue: D row = (lane>>4)*4 + reg, col = lane&15 (HW-verified layout)
    #pragma unroll
    for (int ti = 0; ti < 4; ti++) {
        #pragma unroll
        for (int tj = 0; tj < 2; tj++) {
            int m0 = mBase + wm * 64 + ti * 16 + l4 * 4;
            int n  = nBase + wn * 32 + tj * 16 + l15;
            float bv = bias[n];
            #pragma unroll
            for (int rg = 0; rg < 4; rg++) {
                float v = acc[ti][tj][rg] + bv;
                if (SPLITOUT) {
                    unsigned short h, l;
                    split_bf(v, h, l);
                    Ohi[(size_t)(m0 + rg) * N + n] = h;
                    Olo[(size_t)(m0 + rg) * N + n] = l;
                } else {
                    C[(size_t)(m0 + rg) * N + n] = v;
                }
            }
        }
    }
}

// ---------------- MFMA attention (ws path). Block = (64-q-tile, h, b), 4 waves,
// wave w owns q rows [w*16, w*16+16). Q frags in registers; K row-major + V transposed
// in LDS (hi/lo); online softmax per 16-lane group; P split in per-wave LDS strips.
__global__ __launch_bounds__(256) void attn_mfma(
    const unsigned short* __restrict__ Qhi, const unsigned short* __restrict__ Qlo,
    const unsigned short* __restrict__ Khi, const unsigned short* __restrict__ Klo,
    const unsigned short* __restrict__ Vhi, const unsigned short* __restrict__ Vlo,
    const int* __restrict__ mask, float* __restrict__ scores_out,
    unsigned short* __restrict__ Chi, unsigned short* __restrict__ Clo)
{
    __shared__ unsigned short Kh[64][PIT], Kl[64][PIT];
    __shared__ unsigned short Th[64][PIT], Tl[64][PIT];   // V transposed: [d][k]
    __shared__ unsigned short Ph[4][16][PIT], Pl[4][16][PIT];

    int tid = threadIdx.x;
    int lane = tid & 63, w = tid >> 6;
    int l15 = lane & 15, l4 = lane >> 4;
    int qBase = blockIdx.x * 64;
    int h = blockIdx.y, b = blockIdx.z;

    // Q fragments in registers: row = qBase + w*16 + l15, k-chunks at 0 and 32
    size_t qofs = (size_t)(b * SEQ + qBase + w * 16 + l15) * HIDDEN + h * HDIM;
    bf16x8 qh0 = ld_frag(&Qhi[qofs + l4 * 8]);
    bf16x8 qh1 = ld_frag(&Qhi[qofs + 32 + l4 * 8]);
    bf16x8 ql0 = ld_frag(&Qlo[qofs + l4 * 8]);
    bf16x8 ql1 = ld_frag(&Qlo[qofs + 32 + l4 * 8]);

    f32x4 cacc[4] = {};
    float mrow[4] = {-3.0e38f, -3.0e38f, -3.0e38f, -3.0e38f};
    float rsum[4] = {0.f, 0.f, 0.f, 0.f};

    for (int kt = 0; kt < SEQ; kt += 64) {
        // ---- stage K (row-major) and V (transposed), hi/lo
        {
            int r = tid >> 3, g = tid & 7;
            #pragma unroll
            for (int i = 0; i < 2; i++) {
                int rr = r + i * 32;
                size_t tok = (size_t)(b * SEQ + kt + rr) * HIDDEN + h * HDIM + g * 8;
                *(uint4*)&Kh[rr][g * 8] = *(const uint4*)&Khi[tok];
                *(uint4*)&Kl[rr][g * 8] = *(const uint4*)&Klo[tok];
                union { uint4 u; unsigned short s[8]; } vh, vl;
                vh.u = *(const uint4*)&Vhi[tok];
                vl.u = *(const uint4*)&Vlo[tok];
                #pragma unroll
                for (int dd = 0; dd < 8; dd++) {
                    Th[g * 8 + dd][rr] = vh.s[dd];
                    Tl[g * 8 + dd][rr] = vl.s[dd];
                }
            }
        }
        __syncthreads();

        // ---- S strip = Q K^T (16 x 64), 4 col-tiles
        f32x4 sacc[4] = {};
        #pragma unroll
        for (int ks = 0; ks < 64; ks += 32) {
            int ko = ks + l4 * 8;
            bf16x8 qH = ks ? qh1 : qh0;
            bf16x8 qL = ks ? ql1 : ql0;
            #pragma unroll
            for (int j = 0; j < 4; j++) {
                bf16x8 kH = ld_frag(&Kh[j * 16 + l15][ko]);
                bf16x8 kL = ld_frag(&Kl[j * 16 + l15][ko]);
                sacc[j] = __builtin_amdgcn_mfma_f32_16x16x32_bf16(qH, kH, sacc[j], 0, 0, 0);
                sacc[j] = __builtin_amdgcn_mfma_f32_16x16x32_bf16(qH, kL, sacc[j], 0, 0, 0);
                sacc[j] = __builtin_amdgcn_mfma_f32_16x16x32_bf16(qL, kH, sacc[j], 0, 0, 0);
            }
        }

        // ---- mask + scale + write raw scores
        float sv[4][4];  // [j][rg]
        #pragma unroll
        for (int j = 0; j < 4; j++) {
            #pragma unroll
            for (int rg = 0; rg < 4; rg++) {
                int qrow = qBase + w * 16 + l4 * 4 + rg;
                int kc = kt + j * 16 + l15;
                int mval = mask[(size_t)(b * SEQ + qrow) * SEQ + kc];
                float s = (mval == 0) ? NEGV : sacc[j][rg] * 0.125f;
                scores_out[((size_t)(b * HEADS + h) * SEQ + qrow) * SEQ + kc] = s;
                sv[j][rg] = s;
            }
        }

        // ---- online softmax per row (16-lane group reductions)
        #pragma unroll
        for (int rg = 0; rg < 4; rg++) {
            float tmax = fmaxf(fmaxf(sv[0][rg], sv[1][rg]), fmaxf(sv[2][rg], sv[3][rg]));
            #pragma unroll
            for (int o = 1; o < 16; o <<= 1)
                tmax = fmaxf(tmax, __shfl_xor(tmax, o, 64));
            float mn = fmaxf(mrow[rg], tmax);
            float fac = __expf(mrow[rg] - mn);
            mrow[rg] = mn;
            float ts = 0.f;
            #pragma unroll
            for (int j = 0; j < 4; j++) {
                float e = __expf(sv[j][rg] - mn);
                unsigned short ph, pl;
                split_bf(e, ph, pl);
                Ph[w][l4 * 4 + rg][j * 16 + l15] = ph;
                Pl[w][l4 * 4 + rg][j * 16 + l15] = pl;
                ts += e;
            }
            #pragma unroll
            for (int o = 1; o < 16; o <<= 1)
                ts += __shfl_xor(ts, o, 64);
            rsum[rg] = rsum[rg] * fac + ts;
            cacc[0][rg] *= fac; cacc[1][rg] *= fac;
            cacc[2][rg] *= fac; cacc[3][rg] *= fac;
        }

        // ---- ctx += P V (wave-local P; compiler inserts lgkmcnt for own writes)
        #pragma unroll
        for (int ks = 0; ks < 64; ks += 32) {
            int ko = ks + l4 * 8;
            bf16x8 pH = ld_frag(&Ph[w][l15][ko]);
            bf16x8 pL = ld_frag(&Pl[w][l15][ko]);
            #pragma unroll
            for (int j = 0; j < 4; j++) {
                bf16x8 vH = ld_frag(&Th[j * 16 + l15][ko]);
                bf16x8 vL = ld_frag(&Tl[j * 16 + l15][ko]);
                cacc[j] = __builtin_amdgcn_mfma_f32_16x16x32_bf16(pH, vH, cacc[j], 0, 0, 0);
                cacc[j] = __builtin_amdgcn_mfma_f32_16x16x32_bf16(pH, vL, cacc[j], 0, 0, 0);
                cacc[j] = __builtin_amdgcn_mfma_f32_16x16x32_bf16(pL, vH, cacc[j], 0, 0, 0);
            }
        }
        __syncthreads();
    }

    // ---- epilogue: ctx split-write for the Wo GEMM
    #pragma unroll
    for (int rg = 0; rg < 4; rg++) {
        float inv = 1.0f / rsum[rg];
        int qrow = qBase + w * 16 + l4 * 4 + rg;
        size_t obase = (size_t)(b * SEQ + qrow) * HIDDEN + h * HDIM;
        #pragma unroll
        for (int j = 0; j < 4; j++) {
            float v = cacc[j][rg] * inv;
            unsigned short hh, ll;
            split_bf(v, hh, ll);
            Chi[obase + j * 16 + l15] = hh;
            Clo[obase + j * 16 + l15] = ll;
        }
    }
}

// ================= fp32 fallback path (used only if ws too small) =================
__global__ __launch_bounds__(256) void gemm_bias(const float* __restrict__ A,
    const float* __restrict__ Bw, const float* __restrict__ bias,
    float* __restrict__ C, int M, int N, int K)
{
    __shared__ float As[64][17];
    __shared__ float Bs[16][65];
    int tid = threadIdx.x;
    int tx = tid & 15, ty = tid >> 4;
    int mBase = blockIdx.y * 64, nBase = blockIdx.x * 64;
    float acc[4][4] = {};
    int idA = tid * 4;
    int ra = idA >> 4, ca = idA & 15;
    int rb = idA >> 6, cb = idA & 63;
    int ty4 = ty * 4, tx4 = tx * 4;
    for (int k0 = 0; k0 < K; k0 += 16) {
        float4 fa = *(const float4*)(A + (size_t)(mBase + ra) * K + k0 + ca);
        As[ra][ca + 0] = fa.x; As[ra][ca + 1] = fa.y;
        As[ra][ca + 2] = fa.z; As[ra][ca + 3] = fa.w;
        float4 fb = *(const float4*)(Bw + (size_t)(k0 + rb) * N + nBase + cb);
        Bs[rb][cb + 0] = fb.x; Bs[rb][cb + 1] = fb.y;
        Bs[rb][cb + 2] = fb.z; Bs[rb][cb + 3] = fb.w;
        __syncthreads();
        #pragma unroll
        for (int kk = 0; kk < 16; kk++) {
            float a0 = As[ty4 + 0][kk], a1 = As[ty4 + 1][kk];
            float a2 = As[ty4 + 2][kk], a3 = As[ty4 + 3][kk];
            float b0 = Bs[kk][tx4 + 0], b1 = Bs[kk][tx4 + 1];
            float b2 = Bs[kk][tx4 + 2], b3 = Bs[kk][tx4 + 3];
            acc[0][0] += a0 * b0; acc[0][1] += a0 * b1; acc[0][2] += a0 * b2; acc[0][3] += a0 * b3;
            acc[1][0] += a1 * b0; acc[1][1] += a1 * b1; acc[1][2] += a1 * b2; acc[1][3] += a1 * b3;
            acc[2][0] += a2 * b0; acc[2][1] += a2 * b1; acc[2][2] += a2 * b2; acc[2][3] += a2 * b3;
            acc[3][0] += a3 * b0; acc[3][1] += a3 * b1; acc[3][2] += a3 * b2; acc[3][3] += a3 * b3;
        }
        __syncthreads();
    }
    #pragma unroll
    for (int i = 0; i < 4; i++) {
        int m = mBase + ty4 + i;
        #pragma unroll
        for (int j = 0; j < 4; j++) {
            int n = nBase + tx4 + j;
            C[(size_t)m * N + n] = acc[i][j] + bias[n];
        }
    }
}

__global__ __launch_bounds__(256) void attn_kernel(
    const float* __restrict__ qb, const float* __restrict__ kb, const float* __restrict__ vb,
    const int* __restrict__ mask, float* __restrict__ scores_out, float* __restrict__ ctx,
    int row_cut)
{
    __shared__ float qs[HDIM];
    __shared__ float sc[SEQ];
    __shared__ float red[4];
    __shared__ float part[4][HDIM];
    int tid = threadIdx.x;
    int q = blockIdx.x, h = blockIdx.y, b = blockIdx.z;
    bool wr = (b * HEADS + h) < row_cut;

    if (tid < HDIM)
        qs[tid] = qb[((size_t)(b * SEQ + q)) * HIDDEN + h * HDIM + tid];
    __syncthreads();

    const int* mrow = mask + ((size_t)(b * SEQ + q)) * SEQ;
    const float* kbase = kb + (size_t)b * SEQ * HIDDEN + h * HDIM;
    float* srow = scores_out + (((size_t)(b * HEADS + h)) * SEQ + q) * SEQ;

    float lmax = -3.0e38f;
    for (int j = tid; j < SEQ; j += 256) {
        const float4* kp = (const float4*)(kbase + (size_t)j * HIDDEN);
        float dot = 0.f;
        #pragma unroll
        for (int c = 0; c < 16; c++) {
            float4 u = kp[c];
            dot += qs[c * 4 + 0] * u.x + qs[c * 4 + 1] * u.y
                 + qs[c * 4 + 2] * u.z + qs[c * 4 + 3] * u.w;
        }
        float s = (mrow[j] == 0) ? NEGV : dot * 0.125f;
        sc[j] = s;
        if (wr) srow[j] = s;
        lmax = fmaxf(lmax, s);
    }
    #pragma unroll
    for (int o = 32; o > 0; o >>= 1) lmax = fmaxf(lmax, __shfl_xor(lmax, o, 64));
    __syncthreads();
    if ((tid & 63) == 0) red[tid >> 6] = lmax;
    __syncthreads();
    float m = fmaxf(fmaxf(red[0], red[1]), fmaxf(red[2], red[3]));

    float lsum = 0.f;
    for (int j = tid; j < SEQ; j += 256) {
        float e = __expf(sc[j] - m);
        sc[j] = e;
        lsum += e;
    }
    #pragma unroll
    for (int o = 32; o > 0; o >>= 1) lsum += __shfl_xor(lsum, o, 64);
    __syncthreads();
    if ((tid & 63) == 0) red[tid >> 6] = lsum;
    __syncthreads();
    float inv = 1.0f / (red[0] + red[1] + red[2] + red[3]);

    int d = tid & 63, chunk = tid >> 6;
    const float* vbase = vb + (size_t)b * SEQ * HIDDEN + h * HDIM + d;
    float acc = 0.f;
    int j0 = chunk * 512;
    for (int j = j0; j < j0 + 512; j++)
        acc += sc[j] * vbase[(size_t)j * HIDDEN];
    part[chunk][d] = acc;
    __syncthreads();
    if (tid < HDIM) {
        float r = (part[0][tid] + part[1][tid] + part[2][tid] + part[3][tid]) * inv;
        ctx[((size_t)(b * SEQ + q)) * HIDDEN + h * HDIM + tid] = r;
    }
}

__global__ __launch_bounds__(256) void ln_kernel(float* __restrict__ hbuf,
    const float* __restrict__ x, const float* __restrict__ g, const float* __restrict__ bb,
    float* __restrict__ out)
{
    __shared__ float red[4];
    int row = blockIdx.x, tid = threadIdx.x;
    size_t base = (size_t)row * HIDDEN + tid * 4;
    float4 fh = *(const float4*)(hbuf + base);
    float4 fx = *(const float4*)(x + base);
    float y0 = fh.x + fx.x, y1 = fh.y + fx.y, y2 = fh.z + fx.z, y3 = fh.w + fx.w;

    float s = y0 + y1 + y2 + y3;
    #pragma unroll
    for (int o = 32; o > 0; o >>= 1) s += __shfl_xor(s, o, 64);
    if ((tid & 63) == 0) red[tid >> 6] = s;
    __syncthreads();
    float mu = (red[0] + red[1] + red[2] + red[3]) * (1.f / 1024.f);

    float d0 = y0 - mu, d1 = y1 - mu, d2 = y2 - mu, d3 = y3 - mu;
    float sq = d0 * d0 + d1 * d1 + d2 * d2 + d3 * d3;
    #pragma unroll
    for (int o = 32; o > 0; o >>= 1) sq += __shfl_xor(sq, o, 64);
    __syncthreads();
    if ((tid & 63) == 0) red[tid >> 6] = sq;
    __syncthreads();
    float var = (red[0] + red[1] + red[2] + red[3]) * (1.f / 1024.f);
    float r = rsqrtf(var + 1e-12f);

    float4 fg = *(const float4*)(g + tid * 4);
    float4 fb = *(const float4*)(bb + tid * 4);
    float4 o4;
    o4.x = d0 * r * fg.x + fb.x;
    o4.y = d1 * r * fg.y + fb.y;
    o4.z = d2 * r * fg.z + fb.z;
    o4.w = d3 * r * fg.w + fb.w;
    *(float4*)(out + base) = o4;
}

__global__ __launch_bounds__(256) void score_fixup(const float* __restrict__ x,
    const float* __restrict__ Wq, const float* __restrict__ bq,
    const float* __restrict__ Wk, const float* __restrict__ bk,
    const int* __restrict__ mask, float* __restrict__ scores)
{
    __shared__ float As[64][17];
    __shared__ float Bs[16][65];
    __shared__ float qt[64][65];
    __shared__ float kt[64][65];
    const int b = 1;
    int h = 13 + blockIdx.z;
    int qBase = blockIdx.y * 64, kkBase = blockIdx.x * 64;
    int hcol = h * HDIM;
    int tid = threadIdx.x;
    int tx = tid & 15, ty = tid >> 4;
    int ty4 = ty * 4, tx4 = tx * 4;
    int idA = tid * 4;
    int ra = idA >> 4, ca = idA & 15;
    int rb = idA >> 6, cb = idA & 63;

    for (int pass = 0; pass < 2; pass++) {
        int rowBase = b * SEQ + (pass ? kkBase : qBase);
        const float* W = pass ? Wk : Wq;
        const float* bias = pass ? bk : bq;
        float acc[4][4] = {};
        for (int k0 = 0; k0 < HIDDEN; k0 += 16) {
            float4 fa = *(const float4*)(x + (size_t)(rowBase + ra) * HIDDEN + k0 + ca);
            As[ra][ca + 0] = fa.x; As[ra][ca + 1] = fa.y;
            As[ra][ca + 2] = fa.z; As[ra][ca + 3] = fa.w;
            float4 fb = *(const float4*)(W + (size_t)(k0 + rb) * HIDDEN + hcol + cb);
            Bs[rb][cb + 0] = fb.x; Bs[rb][cb + 1] = fb.y;
            Bs[rb][cb + 2] = fb.z; Bs[rb][cb + 3] = fb.w;
            __syncthreads();
            #pragma unroll
            for (int kk = 0; kk < 16; kk++) {
                float a0 = As[ty4 + 0][kk], a1 = As[ty4 + 1][kk];
                float a2 = As[ty4 + 2][kk], a3 = As[ty4 + 3][kk];
                float b0 = Bs[kk][tx4 + 0], b1 = Bs[kk][tx4 + 1];
                float b2 = Bs[kk][tx4 + 2], b3 = Bs[kk][tx4 + 3];
                acc[0][0] += a0 * b0; acc[0][1] += a0 * b1; acc[0][2] += a0 * b2; acc[0][3] += a0 * b3;
                acc[1][0] += a1 * b0; acc[1][1] += a1 * b1; acc[1][2] += a1 * b2; acc[1][3] += a1 * b3;
                acc[2][0] += a2 * b0; acc[2][1] += a2 * b1; acc[2][2] += a2 * b2; acc[2][3] += a2 * b3;
                acc[3][0] += a3 * b0; acc[3][1] += a3 * b1; acc[3][2] += a3 * b2; acc[3][3] += a3 * b3;
            }
            __syncthreads();
        }
        #pragma unroll
        for (int i = 0; i < 4; i++)
            #pragma unroll
            for (int j = 0; j < 4; j++) {
                float v = acc[i][j] + bias[hcol + tx4 + j];
                if (pass) kt[ty4 + i][tx4 + j] = v;
                else      qt[ty4 + i][tx4 + j] = v;
            }
        __syncthreads();
    }

    float s[4][4] = {};
    for (int d = 0; d < HDIM; d++) {
        float qv0 = qt[ty4 + 0][d], qv1 = qt[ty4 + 1][d];
        float qv2 = qt[ty4 + 2][d], qv3 = qt[ty4 + 3][d];
        float kv0 = kt[tx4 + 0][d], kv1 = kt[tx4 + 1][d];
        float kv2 = kt[tx4 + 2][d], kv3 = kt[tx4 + 3][d];
        s[0][0] += qv0 * kv0; s[0][1] += qv0 * kv1; s[0][2] += qv0 * kv2; s[0][3] += qv0 * kv3;
        s[1][0] += qv1 * kv0; s[1][1] += qv1 * kv1; s[1][2] += qv1 * kv2; s[1][3] += qv1 * kv3;
        s[2][0] += qv2 * kv0; s[2][1] += qv2 * kv1; s[2][2] += qv2 * kv2; s[2][3] += qv2 * kv3;
        s[3][0] += qv3 * kv0; s[3][1] += qv3 * kv1; s[3][2] += qv3 * kv2; s[3][3] += qv3 * kv3;
    }
    #pragma unroll
    for (int i = 0; i < 4; i++) {
        int q = qBase + ty4 + i;
        const int* mrow = mask + ((size_t)(b * SEQ + q)) * SEQ;
        float* srow = scores + (((size_t)(b * HEADS + h)) * SEQ + q) * SEQ;
        #pragma unroll
        for (int j = 0; j < 4; j++) {
            int kk = kkBase + tx4 + j;
            srow[kk] = (mrow[kk] == 0) ? NEGV : s[i][j] * 0.125f;
        }
    }
}

extern "C" void kernel_launch(void* const* d_in, const int* in_sizes, int n_in,
                              void* d_out, int out_size, void* d_ws, size_t ws_size,
                              hipStream_t stream)
{
    const float* x   = (const float*)d_in[0];
    const int*   msk = (const int*)d_in[1];
    const float* Wq  = (const float*)d_in[2];
    const float* bq  = (const float*)d_in[3];
    const float* Wk  = (const float*)d_in[4];
    const float* bk  = (const float*)d_in[5];
    const float* Wv  = (const float*)d_in[6];
    const float* bv  = (const float*)d_in[7];
    const float* Wo  = (const float*)d_in[8];
    const float* bo  = (const float*)d_in[9];
    const float* lng = (const float*)d_in[10];
    const float* lnb = (const float*)d_in[11];

    float* out0   = (float*)d_out;                 // chunk 0: [B*S, HIDDEN]
    float* scores = out0 + (size_t)TOK;            // chunk 1: [B,H,S,S]

    const size_t need = (size_t)3 * TOK * sizeof(float);   // 48 MiB: K/V/ctx splits
    const bool use_ws = (d_ws != nullptr) && (ws_size >= need);

    const int M = BATCH * SEQ;

    if (use_ws) {
        // bf16 hi/lo split arrays: Q split lives in out0 (16 MB, exact fit; dead before
        // the Wo GEMM overwrites it). K/V/ctx splits in ws (6 x 8 MB = 48 MiB, exact fit).
        unsigned short* Qhi = (unsigned short*)out0;
        unsigned short* Qlo = Qhi + (size_t)TOK;
        unsigned short* Khi = (unsigned short*)d_ws;
        unsigned short* Klo = Khi + (size_t)TOK;
        unsigned short* Vhi = Klo + (size_t)TOK;
        unsigned short* Vlo = Vhi + (size_t)TOK;
        unsigned short* Chi = Vlo + (size_t)TOK;
        unsigned short* Clo = Chi + (size_t)TOK;

        dim3 gg(HIDDEN / 64, M / 128);   // (16, 32)
        mfma_gemm<0, 1><<<gg, 256, 0, stream>>>(x, nullptr, nullptr, Wq, bq,
                                                nullptr, Qhi, Qlo, M, HIDDEN, HIDDEN);
        mfma_gemm<0, 1><<<gg, 256, 0, stream>>>(x, nullptr, nullptr, Wk, bk,
                                                nullptr, Khi, Klo, M, HIDDEN, HIDDEN);
        mfma_gemm<0, 1><<<gg, 256, 0, stream>>>(x, nullptr, nullptr, Wv, bv,
                                                nullptr, Vhi, Vlo, M, HIDDEN, HIDDEN);
        attn_mfma<<<dim3(SEQ / 64, HEADS, BATCH), 256, 0, stream>>>(
            Qhi, Qlo, Khi, Klo, Vhi, Vlo, msk, scores, Chi, Clo);
        mfma_gemm<1, 0><<<gg, 256, 0, stream>>>(nullptr, Chi, Clo, Wo, bo,
                                                out0, nullptr, nullptr, M, HIDDEN, HIDDEN);
        ln_kernel<<<M, 256, 0, stream>>>(out0, x, lng, lnb, out0);
    } else {
        // fp32 fallback (scratch carved from score tail + fixup)
        float* Ks = scores + (SC_N - (size_t)3 * TOK);
        float* Vs = Ks + (size_t)TOK;
        float* Cs = Vs + (size_t)TOK;
        float* Qs = out0;
        dim3 gg(HIDDEN / 64, M / 64);
        gemm_bias<<<gg, 256, 0, stream>>>(x, Wq, bq, Qs, M, HIDDEN, HIDDEN);
        gemm_bias<<<gg, 256, 0, stream>>>(x, Wk, bk, Ks, M, HIDDEN, HIDDEN);
        gemm_bias<<<gg, 256, 0, stream>>>(x, Wv, bv, Vs, M, HIDDEN, HIDDEN);
        attn_kernel<<<dim3(SEQ, HEADS, BATCH), 256, 0, stream>>>(Qs, Ks, Vs, msk, scores, Cs, ROW_CUT);
        gemm_bias<<<gg, 256, 0, stream>>>(Cs, Wo, bo, out0, M, HIDDEN, HIDDEN);
        ln_kernel<<<M, 256, 0, stream>>>(out0, x, lng, lnb, out0);
        score_fixup<<<dim3(SEQ / 64, SEQ / 64, 3), 256, 0, stream>>>(x, Wq, bq, Wk, bk, msk, scores);
    }
}